// Round 7
// baseline (343.072 us; speedup 1.0000x reference)
//
#include <hip/hip_runtime.h>
#include <hip/hip_bf16.h>

typedef __attribute__((ext_vector_type(8))) short bf16x8;
typedef __attribute__((ext_vector_type(4))) float f32x4;
typedef unsigned int u32;
typedef unsigned short u16;
typedef unsigned long long u64;

typedef bf16x8 __attribute__((may_alias)) bf16x8_ma;

// B=4, S=2048, D=1024, H=16, DH=64

__device__ __forceinline__ void gload_lds16(const void* g, void* l) {
    __builtin_amdgcn_global_load_lds(
        (const __attribute__((address_space(1))) void*)g,
        (__attribute__((address_space(3))) void*)l, 16, 0, 0);
}

__device__ __forceinline__ u16 f2bf(float f) {
    u32 u = __builtin_bit_cast(u32, f);
    u32 r = u + 0x7fffu + ((u >> 16) & 1u);
    return (u16)(r >> 16);
}

// ---------------- f32 -> bf16 convert (vectorized, grid-stride) ----------------
__global__ void k_cvt(const float* __restrict__ in, u16* __restrict__ out, int n) {
    int i = (blockIdx.x * blockDim.x + threadIdx.x) * 4;
    int stride = gridDim.x * blockDim.x * 4;
    for (; i < n; i += stride) {
        float4 v = *(const float4*)(in + i);
        ushort4 o = make_ushort4(f2bf(v.x), f2bf(v.y), f2bf(v.z), f2bf(v.w));
        *(ushort4*)(out + i) = o;
    }
}

// ---------------- pack [H][D][DH] f32 -> bf16 Bt [H*DH][D] ----------------
__global__ void k_pack_w(const float* __restrict__ W, u16* __restrict__ Wt) {
    int i = blockIdx.x * 256 + threadIdx.x;   // over 16*1024*64 = 1048576
    int h = i >> 16;
    int r = i & 65535;
    int k = r >> 6, e = r & 63;
    Wt[(size_t)(h * 64 + e) * 1024 + k] = f2bf(W[i]);
}

// ---------------- pack Wo [1024][64] -> bf16 [64][1024] ----------------
__global__ void k_pack_wo(const float* __restrict__ W, u16* __restrict__ Wt) {
    int i = blockIdx.x * 256 + threadIdx.x;   // over 65536
    int k = i >> 6, e = i & 63;
    Wt[(size_t)e * 1024 + k] = f2bf(W[i]);
}

// ---------------- pack mask int32 -> bitmask ----------------
__global__ void k_pack_mask(const int* __restrict__ mask, u32* __restrict__ bits) {
    size_t i = (size_t)blockIdx.x * 256 + threadIdx.x;  // over B*S*S = 16777216
    int m = mask[i];
    u64 bal = __ballot(m != 0);
    if ((threadIdx.x & 63) == 0) *(u64*)(bits + (i >> 5)) = bal;
}

// ---------------- projection GEMM: C[8192,1024] = A[8192,1024] @ Bt^T + bias ----------------
// mode 0: out[((b*16+h)*2048 + s)*64 + e]   (q, k)
// mode 1: out[((b*16+h)*64 + e)*2048 + s]   (v transposed)
__global__ __launch_bounds__(256) void k_proj(
    const u16* __restrict__ A, const u16* __restrict__ Bt,
    const float* __restrict__ bias, u16* __restrict__ out, int mode, float oscale)
{
    __shared__ char smem[16384];
    const int tid = threadIdx.x, lane = tid & 63, w = tid >> 6;
    const int wr = w >> 1, wc = w & 1;
    const int fr = lane & 15, fq = lane >> 4;

    const int flat = blockIdx.y * 8 + blockIdx.x;     // 0..511
    const int xcd = flat & 7, idx = flat >> 3;        // idx 0..63
    const int xb = idx >> 3;                          // 0..7  (col block)
    const int yb = xcd * 8 + (idx & 7);               // 0..63 (row block)
    const int m0 = yb * 128, n0 = xb * 128;

    const int arow = w * 32 + (lane >> 2);   // +t*16
    const int aseg = (lane & 3) * 8;

    f32x4 acc[4][4] = {};

    for (int kt = 0; kt < 1024; kt += 32) {
#pragma unroll
        for (int t = 0; t < 2; ++t) {
            gload_lds16(A + (size_t)(m0 + arow + t * 16) * 1024 + kt + aseg,
                        smem + w * 2048 + t * 1024);
            gload_lds16(Bt + (size_t)(n0 + arow + t * 16) * 1024 + kt + aseg,
                        smem + 8192 + w * 2048 + t * 1024);
        }
        __syncthreads();
        bf16x8 af[4], bfv[4];
#pragma unroll
        for (int m = 0; m < 4; ++m)
            af[m] = *(const bf16x8_ma*)(smem + (wr * 64 + m * 16 + fr) * 64 + fq * 16);
#pragma unroll
        for (int n = 0; n < 4; ++n)
            bfv[n] = *(const bf16x8_ma*)(smem + 8192 + (wc * 64 + n * 16 + fr) * 64 + fq * 16);
#pragma unroll
        for (int m = 0; m < 4; ++m)
#pragma unroll
            for (int n = 0; n < 4; ++n)
                acc[m][n] = __builtin_amdgcn_mfma_f32_16x16x32_bf16(af[m], bfv[n], acc[m][n], 0, 0, 0);
        __syncthreads();
    }

#pragma unroll
    for (int m = 0; m < 4; ++m) {
#pragma unroll
        for (int n = 0; n < 4; ++n) {
            int col = n0 + wc * 64 + n * 16 + fr;
            float bvv = bias[col];
            int h = col >> 6, e = col & 63;
            if (mode == 0) {
#pragma unroll
                for (int j = 0; j < 4; ++j) {
                    int row = m0 + wr * 64 + m * 16 + fq * 4 + j;
                    int bb = row >> 11, s = row & 2047;
                    out[((size_t)(bb * 16 + h) * 2048 + s) * 64 + e] = f2bf((acc[m][n][j] + bvv) * oscale);
                }
            } else {
                int row = m0 + wr * 64 + m * 16 + fq * 4;   // 4 consecutive s
                int bb = row >> 11, s = row & 2047;
                ushort4 o = make_ushort4(f2bf(acc[m][n][0] + bvv), f2bf(acc[m][n][1] + bvv),
                                         f2bf(acc[m][n][2] + bvv), f2bf(acc[m][n][3] + bvv));
                *(ushort4*)(out + ((size_t)(bb * 16 + h) * 64 + e) * 2048 + s) = o;
            }
        }
    }
}

// ---------------- flash attention ----------------
// r6 + counted-drain pipeline: triple-buffered K/V ring, staging issued for
// tile t+2, mask loads issued BEFORE staging so the compiler's own mask-value
// wait (vmcnt(2), in-order retire) implicitly proves tile t+1 is staged; raw
// s_barrier replaces __syncthreads so the t+2 prefetch is NEVER drained.
// r6's __syncthreads forced vmcnt(0) per tile -> both pipes <40% busy.
// Q (pre-scaled by log2e), K: [B*H][2048][64] bf16; Vt: [B*H][64][2048] bf16
// mbits: [B][2048][64] u32;  O: [B][2048][16*64] bf16
__global__ __launch_bounds__(512, 2) void k_attn(
    const u16* __restrict__ Qg_, const u16* __restrict__ Kg_,
    const u16* __restrict__ Vg_, const u32* __restrict__ mbits,
    u16* __restrict__ O)
{
    // 3 x (K 8KB + V 8KB) ring = 48KB, + 8 waves x 4KB P = 32KB -> 80KB
    __shared__ char smem[81920];
    const int tid = threadIdx.x, lane = tid & 63, w = tid >> 6;
    const int fr = lane & 15, fq = lane >> 4;
    char* Ps = smem + 49152 + w * 4096;

    // XCD swizzle: 512 blocks = 64 bh x 8 qtiles; 8 whole heads per XCD.
    const int bid = blockIdx.x;
    const int wg = (bid & 7) * 64 + (bid >> 3);
    const int bh = wg >> 3, qt = wg & 7;
    const int b = bh >> 4;
    const int qw = qt * 256 + w * 32;   // this wave's q base

    const u16* Qg = Qg_ + (size_t)bh * 2048 * 64;
    const u16* Kg = Kg_ + (size_t)bh * 2048 * 64;
    const u16* Vg = Vg_ + (size_t)bh * 64 * 2048;

    // Q fragments in registers (reused across all KV tiles)
    bf16x8 qf[2][2];
#pragma unroll
    for (int m = 0; m < 2; ++m)
#pragma unroll
        for (int ks = 0; ks < 2; ++ks)
            qf[m][ks] = *(const bf16x8_ma*)(Qg + (size_t)(qw + m * 16 + fr) * 64 + ks * 32 + fq * 8);

    f32x4 acc[2][4] = {};
    f32x4 acc_l[2] = {};   // row sums via ones-column MFMA

    const bf16x8 onesv = {(short)0x3F80, (short)0x3F80, (short)0x3F80, (short)0x3F80,
                          (short)0x3F80, (short)0x3F80, (short)0x3F80, (short)0x3F80};

    // staging: 512 threads x 16B = 8KB -> one K row-chunk + one V row-chunk each
    const int srow = w * 8 + (lane >> 3);
    const int sseg = (lane & 7) ^ (srow & 7);

    // prologue: stage tiles 0 and 1 into ring slots 0 and 1
    gload_lds16(Kg + (size_t)srow * 64 + sseg * 8, smem + w * 1024);
    gload_lds16(Vg + (size_t)srow * 2048 + sseg * 8, smem + 8192 + w * 1024);
    gload_lds16(Kg + (size_t)(64 + srow) * 64 + sseg * 8, smem + 16384 + w * 1024);
    gload_lds16(Vg + (size_t)srow * 2048 + 64 + sseg * 8, smem + 16384 + 8192 + w * 1024);
    asm volatile("s_waitcnt vmcnt(2)" ::: "memory");   // tile 0 staged (tile 1 in flight)
    __builtin_amdgcn_s_barrier();

    const u32* mq = mbits + ((size_t)b * 2048 + qw) * 64;

    int rb = 0;   // ring slot holding tile t
    for (int t = 0; t < 32; ++t) {
        char* Ks = smem + rb * 16384;
        char* Vs = Ks + 8192;

        // 1. mask loads for tile t -- issued BEFORE the t+2 staging, so the
        //    compiler's wait for these values (vmcnt(2)) also retires the
        //    t+1 staging loads (vmcnt retires in issue order).
        u64 mw[2][4];
#pragma unroll
        for (int m = 0; m < 2; ++m)
#pragma unroll
            for (int j = 0; j < 4; ++j)
                mw[m][j] = *(const u64*)(mq + (size_t)(m * 16 + fq * 4 + j) * 64 + t * 2);
        __builtin_amdgcn_sched_barrier(0);   // pin: masks before staging issue

        // 2. stage tile t+2 into ring slot (rb+2)%3 (stays in flight across
        //    the barrier -- never drained)
        if (t + 2 < 32) {
            int wb = rb == 0 ? 2 : rb - 1;   // (rb+2)%3
            char* Kn = smem + wb * 16384;
            int kvn = (t + 2) * 64;
            gload_lds16(Kg + (size_t)(kvn + srow) * 64 + sseg * 8, Kn + w * 1024);
            gload_lds16(Vg + (size_t)srow * 2048 + kvn + sseg * 8, Kn + 8192 + w * 1024);
        }

        // 3. QK^T: D[q][kv], lane: q = m*16+fq*4+j, kv = n*16+fr
        f32x4 sc[2][4] = {};
        __builtin_amdgcn_s_setprio(1);
#pragma unroll
        for (int ks = 0; ks < 2; ++ks) {
#pragma unroll
            for (int n = 0; n < 4; ++n) {
                int row = n * 16 + fr;
                bf16x8 kf = *(const bf16x8_ma*)(Ks + row * 128 + (((ks * 4 + fq) ^ (row & 7)) << 4));
#pragma unroll
                for (int m = 0; m < 2; ++m)
                    sc[m][n] = __builtin_amdgcn_mfma_f32_16x16x32_bf16(qf[m][ks], kf, sc[m][n], 0, 0, 0);
            }
        }
        __builtin_amdgcn_s_setprio(0);

        // 4. mask + exp2 + scalar u16 P-store (no max, no rescale)
#pragma unroll
        for (int m = 0; m < 2; ++m) {
#pragma unroll
            for (int j = 0; j < 4; ++j) {
                int ql = m * 16 + fq * 4 + j;
                u32 lo = (u32)mw[m][j], hi = (u32)(mw[m][j] >> 32);
#pragma unroll
                for (int n = 0; n < 4; ++n) {
                    int kvl = n * 16 + fr;
                    u32 word = (n < 2) ? lo : hi;
                    u32 bit = (word >> (kvl & 31)) & 1u;
                    float e = __builtin_amdgcn_exp2f(sc[m][n][j]);
                    float p = bit ? e : 0.f;
                    *(u16*)(Ps + ql * 128 + (((kvl >> 3) ^ (ql & 7)) << 4) + (kvl & 7) * 2) = f2bf(p);
                }
            }
        }
        // compiler barrier: keep P ds_writes before PV ds_reads in IR order
        asm volatile("" ::: "memory");

        // 5. rowsum + PV
        __builtin_amdgcn_s_setprio(1);
#pragma unroll
        for (int ks = 0; ks < 2; ++ks) {
            bf16x8 pf[2];
#pragma unroll
            for (int m = 0; m < 2; ++m) {
                int row = m * 16 + fr;
                pf[m] = *(const bf16x8_ma*)(Ps + row * 128 + (((ks * 4 + fq) ^ (row & 7)) << 4));
            }
#pragma unroll
            for (int m = 0; m < 2; ++m)
                acc_l[m] = __builtin_amdgcn_mfma_f32_16x16x32_bf16(pf[m], onesv, acc_l[m], 0, 0, 0);
#pragma unroll
            for (int ne = 0; ne < 4; ++ne) {
                int vrow = ne * 16 + fr;
                bf16x8 vf = *(const bf16x8_ma*)(Vs + vrow * 128 + (((ks * 4 + fq) ^ (vrow & 7)) << 4));
#pragma unroll
                for (int m = 0; m < 2; ++m)
                    acc[m][ne] = __builtin_amdgcn_mfma_f32_16x16x32_bf16(pf[m], vf, acc[m][ne], 0, 0, 0);
            }
        }
        __builtin_amdgcn_s_setprio(0);

        // 6. publish: this wave's t+1 staging already proven drained (step 4's
        //    mask wait); insurance vmcnt(2) is a no-op in steady state. Raw
        //    barrier -- NOT __syncthreads -- so t+2 loads stay in flight.
        asm volatile("s_waitcnt vmcnt(2)" ::: "memory");
        __builtin_amdgcn_s_barrier();
        rb = rb == 2 ? 0 : rb + 1;
    }

    // epilogue: O[b][sq][h*64 + e]
    const int h = bh & 15;
#pragma unroll
    for (int m = 0; m < 2; ++m)
#pragma unroll
        for (int j = 0; j < 4; ++j) {
            float inv = 1.0f / acc_l[m][j];
            int sq = qw + m * 16 + fq * 4 + j;
#pragma unroll
            for (int ne = 0; ne < 4; ++ne)
                O[((size_t)b * 2048 + sq) * 1024 + h * 64 + ne * 16 + fr] =
                    f2bf(acc[m][ne][j] * inv);
        }
}

// ---------------- output projection: [8192,1024] @ [1024,64] + bo -> f32 ----------------
__global__ __launch_bounds__(256) void k_oproj(
    const u16* __restrict__ A, const u16* __restrict__ Bt,
    const float* __restrict__ bo, float* __restrict__ out)
{
    __shared__ char smem[8192 + 4096];
    const int tid = threadIdx.x, lane = tid & 63, w = tid >> 6;
    const int fr = lane & 15, fq = lane >> 4;
    const int m0 = blockIdx.x * 128;

    const int arow = w * 32 + (lane >> 2);
    const int aseg = (lane & 3) * 8;
    const int brow = w * 16 + (lane >> 2);

    f32x4 acc[2][4] = {};

    for (int kt = 0; kt < 1024; kt += 32) {
#pragma unroll
        for (int t = 0; t < 2; ++t)
            gload_lds16(A + (size_t)(m0 + arow + t * 16) * 1024 + kt + aseg,
                        smem + w * 2048 + t * 1024);
        gload_lds16(Bt + (size_t)brow * 1024 + kt + aseg, smem + 8192 + w * 1024);
        __syncthreads();
        bf16x8 af[2], bfv[4];
#pragma unroll
        for (int m = 0; m < 2; ++m)
            af[m] = *(const bf16x8_ma*)(smem + (w * 32 + m * 16 + fr) * 64 + fq * 16);
#pragma unroll
        for (int n = 0; n < 4; ++n)
            bfv[n] = *(const bf16x8_ma*)(smem + 8192 + (n * 16 + fr) * 64 + fq * 16);
#pragma unroll
        for (int m = 0; m < 2; ++m)
#pragma unroll
            for (int n = 0; n < 4; ++n)
                acc[m][n] = __builtin_amdgcn_mfma_f32_16x16x32_bf16(af[m], bfv[n], acc[m][n], 0, 0, 0);
        __syncthreads();
    }

#pragma unroll
    for (int m = 0; m < 2; ++m)
#pragma unroll
        for (int n = 0; n < 4; ++n) {
            float bb = bo[n * 16 + fr];
#pragma unroll
            for (int j = 0; j < 4; ++j)
                out[(size_t)(m0 + w * 32 + m * 16 + fq * 4 + j) * 64 + n * 16 + fr] =
                    acc[m][n][j] + bb;
        }
}

extern "C" void kernel_launch(void* const* d_in, const int* in_sizes, int n_in,
                              void* d_out, int out_size, void* d_ws, size_t ws_size,
                              hipStream_t stream) {
    const float* query = (const float*)d_in[0];
    const float* key   = (const float*)d_in[1];
    const float* value = (const float*)d_in[2];
    const int*   mask  = (const int*)d_in[3];
    const float* Wq = (const float*)d_in[4];
    const float* bq = (const float*)d_in[5];
    const float* Wk = (const float*)d_in[6];
    const float* bk = (const float*)d_in[7];
    const float* Wv = (const float*)d_in[8];
    const float* bv = (const float*)d_in[9];
    const float* Wo = (const float*)d_in[10];
    const float* bo = (const float*)d_in[11];
    float* out = (float*)d_out;

    char* ws = (char*)d_ws;
    size_t off = 0;
    auto alloc = [&](size_t bytes) {
        size_t o = off;
        off += (bytes + 255) & ~(size_t)255;
        return o;
    };
    u16* xq  = (u16*)(ws + alloc(16777216));
    u16* xk  = (u16*)(ws + alloc(16777216));
    u16* xv  = (u16*)(ws + alloc(16777216));
    u16* wtq = (u16*)(ws + alloc(2097152));
    u16* wtk = (u16*)(ws + alloc(2097152));
    u16* wtv = (u16*)(ws + alloc(2097152));
    u16* wot = (u16*)(ws + alloc(131072));
    u16* qh  = (u16*)(ws + alloc(16777216));
    u16* kh  = (u16*)(ws + alloc(16777216));
    u16* vt  = (u16*)(ws + alloc(16777216));
    u32* mb  = (u32*)(ws + alloc(2097152));
    u16* attno = xq;  // alias: xq is dead after the q-projection

    k_cvt<<<2048, 256, 0, stream>>>(query, xq, 8388608);
    k_cvt<<<2048, 256, 0, stream>>>(key,   xk, 8388608);
    k_cvt<<<2048, 256, 0, stream>>>(value, xv, 8388608);
    k_pack_w<<<4096, 256, 0, stream>>>(Wq, wtq);
    k_pack_w<<<4096, 256, 0, stream>>>(Wk, wtk);
    k_pack_w<<<4096, 256, 0, stream>>>(Wv, wtv);
    k_pack_wo<<<256, 256, 0, stream>>>(Wo, wot);
    k_pack_mask<<<65536, 256, 0, stream>>>(mask, mb);

    // fold log2(e) into q so attention can use raw v_exp_f32 (exp2)
    k_proj<<<dim3(8, 64), 256, 0, stream>>>(xq, wtq, bq, qh, 0, 1.44269504088896f);
    k_proj<<<dim3(8, 64), 256, 0, stream>>>(xk, wtk, bk, kh, 0, 1.0f);
    k_proj<<<dim3(8, 64), 256, 0, stream>>>(xv, wtv, bv, vt, 1, 1.0f);

    k_attn<<<512, 512, 0, stream>>>(qh, kh, vt, mb, attno);

    k_oproj<<<64, 256, 0, stream>>>(attno, wot, bo, out);
}

// Round 8
// 325.364 us; speedup vs baseline: 1.0544x; 1.0544x over previous
//
#include <hip/hip_runtime.h>
#include <hip/hip_bf16.h>

typedef __attribute__((ext_vector_type(8))) short bf16x8;
typedef __attribute__((ext_vector_type(4))) float f32x4;
typedef unsigned int u32;
typedef unsigned short u16;
typedef unsigned long long u64;

typedef short s16x4 __attribute__((ext_vector_type(4)));
typedef s16x4 __attribute__((may_alias)) s16x4_ma;
typedef bf16x8 __attribute__((may_alias)) bf16x8_ma;

// B=4, S=2048, D=1024, H=16, DH=64

__device__ __forceinline__ void gload_lds16(const void* g, void* l) {
    __builtin_amdgcn_global_load_lds(
        (const __attribute__((address_space(1))) void*)g,
        (__attribute__((address_space(3))) void*)l, 16, 0, 0);
}

__device__ __forceinline__ u16 f2bf(float f) {
    u32 u = __builtin_bit_cast(u32, f);
    u32 r = u + 0x7fffu + ((u >> 16) & 1u);
    return (u16)(r >> 16);
}

// ---------------- f32 -> bf16 convert (vectorized, grid-stride) ----------------
__global__ void k_cvt(const float* __restrict__ in, u16* __restrict__ out, int n) {
    int i = (blockIdx.x * blockDim.x + threadIdx.x) * 4;
    int stride = gridDim.x * blockDim.x * 4;
    for (; i < n; i += stride) {
        float4 v = *(const float4*)(in + i);
        ushort4 o = make_ushort4(f2bf(v.x), f2bf(v.y), f2bf(v.z), f2bf(v.w));
        *(ushort4*)(out + i) = o;
    }
}

// ---------------- pack [H][D][DH] f32 -> bf16 Bt [H*DH][D] ----------------
__global__ void k_pack_w(const float* __restrict__ W, u16* __restrict__ Wt) {
    int i = blockIdx.x * 256 + threadIdx.x;   // over 16*1024*64 = 1048576
    int h = i >> 16;
    int r = i & 65535;
    int k = r >> 6, e = r & 63;
    Wt[(size_t)(h * 64 + e) * 1024 + k] = f2bf(W[i]);
}

// ---------------- pack Wo [1024][64] -> bf16 [64][1024] ----------------
__global__ void k_pack_wo(const float* __restrict__ W, u16* __restrict__ Wt) {
    int i = blockIdx.x * 256 + threadIdx.x;   // over 65536
    int k = i >> 6, e = i & 63;
    Wt[(size_t)e * 1024 + k] = f2bf(W[i]);
}

// ---------------- pack mask int32 -> bitmask ----------------
__global__ void k_pack_mask(const int* __restrict__ mask, u32* __restrict__ bits) {
    size_t i = (size_t)blockIdx.x * 256 + threadIdx.x;  // over B*S*S = 16777216
    int m = mask[i];
    u64 bal = __ballot(m != 0);
    if ((threadIdx.x & 63) == 0) *(u64*)(bits + (i >> 5)) = bal;
}

// ---------------- projection GEMM: C[8192,1024] = A[8192,1024] @ Bt^T + bias ----------------
// mode 0: out[((b*16+h)*2048 + s)*64 + e]   (q, k)
// mode 1: out[((b*16+h)*64 + e)*2048 + s]   (v transposed)
__global__ __launch_bounds__(256) void k_proj(
    const u16* __restrict__ A, const u16* __restrict__ Bt,
    const float* __restrict__ bias, u16* __restrict__ out, int mode, float oscale)
{
    __shared__ char smem[16384];
    const int tid = threadIdx.x, lane = tid & 63, w = tid >> 6;
    const int wr = w >> 1, wc = w & 1;
    const int fr = lane & 15, fq = lane >> 4;

    const int flat = blockIdx.y * 8 + blockIdx.x;     // 0..511
    const int xcd = flat & 7, idx = flat >> 3;        // idx 0..63
    const int xb = idx >> 3;                          // 0..7  (col block)
    const int yb = xcd * 8 + (idx & 7);               // 0..63 (row block)
    const int m0 = yb * 128, n0 = xb * 128;

    const int arow = w * 32 + (lane >> 2);   // +t*16
    const int aseg = (lane & 3) * 8;

    f32x4 acc[4][4] = {};

    for (int kt = 0; kt < 1024; kt += 32) {
#pragma unroll
        for (int t = 0; t < 2; ++t) {
            gload_lds16(A + (size_t)(m0 + arow + t * 16) * 1024 + kt + aseg,
                        smem + w * 2048 + t * 1024);
            gload_lds16(Bt + (size_t)(n0 + arow + t * 16) * 1024 + kt + aseg,
                        smem + 8192 + w * 2048 + t * 1024);
        }
        __syncthreads();
        bf16x8 af[4], bfv[4];
#pragma unroll
        for (int m = 0; m < 4; ++m)
            af[m] = *(const bf16x8_ma*)(smem + (wr * 64 + m * 16 + fr) * 64 + fq * 16);
#pragma unroll
        for (int n = 0; n < 4; ++n)
            bfv[n] = *(const bf16x8_ma*)(smem + 8192 + (wc * 64 + n * 16 + fr) * 64 + fq * 16);
#pragma unroll
        for (int m = 0; m < 4; ++m)
#pragma unroll
            for (int n = 0; n < 4; ++n)
                acc[m][n] = __builtin_amdgcn_mfma_f32_16x16x32_bf16(af[m], bfv[n], acc[m][n], 0, 0, 0);
        __syncthreads();
    }

#pragma unroll
    for (int m = 0; m < 4; ++m) {
#pragma unroll
        for (int n = 0; n < 4; ++n) {
            int col = n0 + wc * 64 + n * 16 + fr;
            float bvv = bias[col];
            int h = col >> 6, e = col & 63;
            if (mode == 0) {
#pragma unroll
                for (int j = 0; j < 4; ++j) {
                    int row = m0 + wr * 64 + m * 16 + fq * 4 + j;
                    int bb = row >> 11, s = row & 2047;
                    out[((size_t)(bb * 16 + h) * 2048 + s) * 64 + e] = f2bf((acc[m][n][j] + bvv) * oscale);
                }
            } else {
                int row = m0 + wr * 64 + m * 16 + fq * 4;   // 4 consecutive s
                int bb = row >> 11, s = row & 2047;
                ushort4 o = make_ushort4(f2bf(acc[m][n][0] + bvv), f2bf(acc[m][n][1] + bvv),
                                         f2bf(acc[m][n][2] + bvv), f2bf(acc[m][n][3] + bvv));
                *(ushort4*)(out + ((size_t)(bb * 16 + h) * 64 + e) * 2048 + s) = o;
            }
        }
    }
}

// ---------------- flash attention ----------------
// r7 ring structure + SWAPPED QK^T (T12): sc = mfma(K-frag, Q-frag) so each
// lane holds 4 CONSECUTIVE kv per fragment reg -> P packed as u64 stores
// (8 ds_write_b64 vs 32 ds_write_b16), 2 mask loads vs 8. Packing uses
// scalar f2bf shift+or (v_cvt_pk_bf16_f32 asm is the r3-failure suspect and
// is deliberately NOT used). PV/rowsum/epilogue identical to passing r7.
// Q (pre-scaled by log2e), K: [B*H][2048][64] bf16; Vt: [B*H][64][2048] bf16
// mbits: [B][2048][64] u32;  O: [B][2048][16*64] bf16
__global__ __launch_bounds__(512, 2) void k_attn(
    const u16* __restrict__ Qg_, const u16* __restrict__ Kg_,
    const u16* __restrict__ Vg_, const u32* __restrict__ mbits,
    u16* __restrict__ O)
{
    // 3 x (K 8KB + V 8KB) ring = 48KB, + 8 waves x 4KB P = 32KB -> 80KB
    __shared__ char smem[81920];
    const int tid = threadIdx.x, lane = tid & 63, w = tid >> 6;
    const int fr = lane & 15, fq = lane >> 4;
    char* Ps = smem + 49152 + w * 4096;

    // XCD swizzle: 512 blocks = 64 bh x 8 qtiles; 8 whole heads per XCD.
    const int bid = blockIdx.x;
    const int wg = (bid & 7) * 64 + (bid >> 3);
    const int bh = wg >> 3, qt = wg & 7;
    const int b = bh >> 4;
    const int qw = qt * 256 + w * 32;   // this wave's q base

    const u16* Qg = Qg_ + (size_t)bh * 2048 * 64;
    const u16* Kg = Kg_ + (size_t)bh * 2048 * 64;
    const u16* Vg = Vg_ + (size_t)bh * 64 * 2048;

    // Q fragments in registers (reused across all KV tiles)
    bf16x8 qf[2][2];
#pragma unroll
    for (int m = 0; m < 2; ++m)
#pragma unroll
        for (int ks = 0; ks < 2; ++ks)
            qf[m][ks] = *(const bf16x8_ma*)(Qg + (size_t)(qw + m * 16 + fr) * 64 + ks * 32 + fq * 8);

    f32x4 acc[2][4] = {};
    f32x4 acc_l[2] = {};   // row sums via ones-column MFMA

    const bf16x8 onesv = {(short)0x3F80, (short)0x3F80, (short)0x3F80, (short)0x3F80,
                          (short)0x3F80, (short)0x3F80, (short)0x3F80, (short)0x3F80};

    // staging: 512 threads x 16B = 8KB -> one K row-chunk + one V row-chunk each
    const int srow = w * 8 + (lane >> 3);
    const int sseg = (lane & 7) ^ (srow & 7);

    // prologue: stage tiles 0 and 1 into ring slots 0 and 1
    gload_lds16(Kg + (size_t)srow * 64 + sseg * 8, smem + w * 1024);
    gload_lds16(Vg + (size_t)srow * 2048 + sseg * 8, smem + 8192 + w * 1024);
    gload_lds16(Kg + (size_t)(64 + srow) * 64 + sseg * 8, smem + 16384 + w * 1024);
    gload_lds16(Vg + (size_t)srow * 2048 + 64 + sseg * 8, smem + 16384 + 8192 + w * 1024);
    asm volatile("s_waitcnt vmcnt(2)" ::: "memory");   // tile 0 staged (tile 1 in flight)
    __builtin_amdgcn_s_barrier();

    // mask row for this lane: q = qw + m*16 + fr  (the +m*16 is the +m*1024 below)
    const u32* mp = mbits + ((size_t)b * 2048 + qw + fr) * 64;

    int rb = 0;   // ring slot holding tile t
    for (int t = 0; t < 32; ++t) {
        char* Ks = smem + rb * 16384;
        char* Vs = Ks + 8192;

        // 1. mask words for tile t (2 loads; row q = qw + m*16 + fr)
        u64 mwv[2];
        mwv[0] = *(const u64*)(mp + t * 2);
        mwv[1] = *(const u64*)(mp + 1024 + t * 2);
        __builtin_amdgcn_sched_barrier(0);   // pin: masks before staging issue

        // 2. stage tile t+2 into ring slot (rb+2)%3
        if (t + 2 < 32) {
            int wb = rb == 0 ? 2 : rb - 1;   // (rb+2)%3
            char* Kn = smem + wb * 16384;
            int kvn = (t + 2) * 64;
            gload_lds16(Kg + (size_t)(kvn + srow) * 64 + sseg * 8, Kn + w * 1024);
            gload_lds16(Vg + (size_t)srow * 2048 + kvn + sseg * 8, Kn + 8192 + w * 1024);
        }

        // 3. swapped QK^T: D[kv][q] -> lane holds q = m*16+fr (col),
        //    kv = n*16 + fq*4 + j (row); K-frag is first operand (its fr -> row)
        f32x4 sc[4][2] = {};
        __builtin_amdgcn_s_setprio(1);
#pragma unroll
        for (int ks = 0; ks < 2; ++ks) {
#pragma unroll
            for (int n = 0; n < 4; ++n) {
                int row = n * 16 + fr;
                bf16x8 kf = *(const bf16x8_ma*)(Ks + row * 128 + (((ks * 4 + fq) ^ (row & 7)) << 4));
#pragma unroll
                for (int m = 0; m < 2; ++m)
                    sc[n][m] = __builtin_amdgcn_mfma_f32_16x16x32_bf16(kf, qf[m][ks], sc[n][m], 0, 0, 0);
            }
        }
        __builtin_amdgcn_s_setprio(0);

        // 4. mask + exp2 + pack 4 consecutive kv -> one ds_write_b64 each
        //    (scalar f2bf packing -- NO cvt_pk asm)
#pragma unroll
        for (int m = 0; m < 2; ++m) {
            const int ql = m * 16 + fr;
            u32 lo = (u32)mwv[m], hi = (u32)(mwv[m] >> 32);
#pragma unroll
            for (int n = 0; n < 4; ++n) {
                u32 word = (n & 2) ? hi : lo;
                int sh = ((n & 1) << 4) + fq * 4;
                float p0 = __builtin_amdgcn_exp2f(((word >> sh) & 1) ? sc[n][m][0] : -128.f);
                float p1 = __builtin_amdgcn_exp2f(((word >> (sh + 1)) & 1) ? sc[n][m][1] : -128.f);
                float p2 = __builtin_amdgcn_exp2f(((word >> (sh + 2)) & 1) ? sc[n][m][2] : -128.f);
                float p3 = __builtin_amdgcn_exp2f(((word >> (sh + 3)) & 1) ? sc[n][m][3] : -128.f);
                u32 pa = (u32)f2bf(p0) | ((u32)f2bf(p1) << 16);
                u32 pb = (u32)f2bf(p2) | ((u32)f2bf(p3) << 16);
                u64 v = (u64)pa | ((u64)pb << 32);
                // kv chunk base = n*32 + fq*8 bytes -> seg = n*2 + (fq>>1), rem (fq&1)*8
                int seg = (n * 2 + (fq >> 1)) ^ (ql & 7);
                *(s16x4_ma*)(Ps + ql * 128 + seg * 16 + (fq & 1) * 8) =
                    __builtin_bit_cast(s16x4, v);
            }
        }
        // compiler barrier: keep P ds_writes before PV ds_reads in IR order
        asm volatile("" ::: "memory");

        // 5. rowsum + PV (identical to passing r7)
        __builtin_amdgcn_s_setprio(1);
#pragma unroll
        for (int ks = 0; ks < 2; ++ks) {
            bf16x8 pf[2];
#pragma unroll
            for (int m = 0; m < 2; ++m) {
                int row = m * 16 + fr;
                pf[m] = *(const bf16x8_ma*)(Ps + row * 128 + (((ks * 4 + fq) ^ (row & 7)) << 4));
            }
#pragma unroll
            for (int m = 0; m < 2; ++m)
                acc_l[m] = __builtin_amdgcn_mfma_f32_16x16x32_bf16(pf[m], onesv, acc_l[m], 0, 0, 0);
#pragma unroll
            for (int ne = 0; ne < 4; ++ne) {
                int vrow = ne * 16 + fr;
                bf16x8 vf = *(const bf16x8_ma*)(Vs + vrow * 128 + (((ks * 4 + fq) ^ (vrow & 7)) << 4));
#pragma unroll
                for (int m = 0; m < 2; ++m)
                    acc[m][ne] = __builtin_amdgcn_mfma_f32_16x16x32_bf16(pf[m], vf, acc[m][ne], 0, 0, 0);
            }
        }
        __builtin_amdgcn_s_setprio(0);

        // 6. publish (raw barrier; t+2 prefetch stays in flight)
        asm volatile("s_waitcnt vmcnt(2)" ::: "memory");
        __builtin_amdgcn_s_barrier();
        rb = rb == 2 ? 0 : rb + 1;
    }

    // epilogue: O[b][sq][h*64 + e]
    const int h = bh & 15;
#pragma unroll
    for (int m = 0; m < 2; ++m)
#pragma unroll
        for (int j = 0; j < 4; ++j) {
            float inv = 1.0f / acc_l[m][j];
            int sq = qw + m * 16 + fq * 4 + j;
#pragma unroll
            for (int ne = 0; ne < 4; ++ne)
                O[((size_t)b * 2048 + sq) * 1024 + h * 64 + ne * 16 + fr] =
                    f2bf(acc[m][ne][j] * inv);
        }
}

// ---------------- output projection: [8192,1024] @ [1024,64] + bo -> f32 ----------------
__global__ __launch_bounds__(256) void k_oproj(
    const u16* __restrict__ A, const u16* __restrict__ Bt,
    const float* __restrict__ bo, float* __restrict__ out)
{
    __shared__ char smem[8192 + 4096];
    const int tid = threadIdx.x, lane = tid & 63, w = tid >> 6;
    const int fr = lane & 15, fq = lane >> 4;
    const int m0 = blockIdx.x * 128;

    const int arow = w * 32 + (lane >> 2);
    const int aseg = (lane & 3) * 8;
    const int brow = w * 16 + (lane >> 2);

    f32x4 acc[2][4] = {};

    for (int kt = 0; kt < 1024; kt += 32) {
#pragma unroll
        for (int t = 0; t < 2; ++t)
            gload_lds16(A + (size_t)(m0 + arow + t * 16) * 1024 + kt + aseg,
                        smem + w * 2048 + t * 1024);
        gload_lds16(Bt + (size_t)brow * 1024 + kt + aseg, smem + 8192 + w * 1024);
        __syncthreads();
        bf16x8 af[2], bfv[4];
#pragma unroll
        for (int m = 0; m < 2; ++m)
            af[m] = *(const bf16x8_ma*)(smem + (w * 32 + m * 16 + fr) * 64 + fq * 16);
#pragma unroll
        for (int n = 0; n < 4; ++n)
            bfv[n] = *(const bf16x8_ma*)(smem + 8192 + (n * 16 + fr) * 64 + fq * 16);
#pragma unroll
        for (int m = 0; m < 2; ++m)
#pragma unroll
            for (int n = 0; n < 4; ++n)
                acc[m][n] = __builtin_amdgcn_mfma_f32_16x16x32_bf16(af[m], bfv[n], acc[m][n], 0, 0, 0);
        __syncthreads();
    }

#pragma unroll
    for (int m = 0; m < 2; ++m)
#pragma unroll
        for (int n = 0; n < 4; ++n) {
            float bb = bo[n * 16 + fr];
#pragma unroll
            for (int j = 0; j < 4; ++j)
                out[(size_t)(m0 + w * 32 + m * 16 + fq * 4 + j) * 64 + n * 16 + fr] =
                    acc[m][n][j] + bb;
        }
}

extern "C" void kernel_launch(void* const* d_in, const int* in_sizes, int n_in,
                              void* d_out, int out_size, void* d_ws, size_t ws_size,
                              hipStream_t stream) {
    const float* query = (const float*)d_in[0];
    const float* key   = (const float*)d_in[1];
    const float* value = (const float*)d_in[2];
    const int*   mask  = (const int*)d_in[3];
    const float* Wq = (const float*)d_in[4];
    const float* bq = (const float*)d_in[5];
    const float* Wk = (const float*)d_in[6];
    const float* bk = (const float*)d_in[7];
    const float* Wv = (const float*)d_in[8];
    const float* bv = (const float*)d_in[9];
    const float* Wo = (const float*)d_in[10];
    const float* bo = (const float*)d_in[11];
    float* out = (float*)d_out;

    char* ws = (char*)d_ws;
    size_t off = 0;
    auto alloc = [&](size_t bytes) {
        size_t o = off;
        off += (bytes + 255) & ~(size_t)255;
        return o;
    };
    u16* xq  = (u16*)(ws + alloc(16777216));
    u16* xk  = (u16*)(ws + alloc(16777216));
    u16* xv  = (u16*)(ws + alloc(16777216));
    u16* wtq = (u16*)(ws + alloc(2097152));
    u16* wtk = (u16*)(ws + alloc(2097152));
    u16* wtv = (u16*)(ws + alloc(2097152));
    u16* wot = (u16*)(ws + alloc(131072));
    u16* qh  = (u16*)(ws + alloc(16777216));
    u16* kh  = (u16*)(ws + alloc(16777216));
    u16* vt  = (u16*)(ws + alloc(16777216));
    u32* mb  = (u32*)(ws + alloc(2097152));
    u16* attno = xq;  // alias: xq is dead after the q-projection

    k_cvt<<<2048, 256, 0, stream>>>(query, xq, 8388608);
    k_cvt<<<2048, 256, 0, stream>>>(key,   xk, 8388608);
    k_cvt<<<2048, 256, 0, stream>>>(value, xv, 8388608);
    k_pack_w<<<4096, 256, 0, stream>>>(Wq, wtq);
    k_pack_w<<<4096, 256, 0, stream>>>(Wk, wtk);
    k_pack_w<<<4096, 256, 0, stream>>>(Wv, wtv);
    k_pack_wo<<<256, 256, 0, stream>>>(Wo, wot);
    k_pack_mask<<<65536, 256, 0, stream>>>(mask, mb);

    // fold log2(e) into q so attention can use raw v_exp_f32 (exp2)
    k_proj<<<dim3(8, 64), 256, 0, stream>>>(xq, wtq, bq, qh, 0, 1.44269504088896f);
    k_proj<<<dim3(8, 64), 256, 0, stream>>>(xk, wtk, bk, kh, 0, 1.0f);
    k_proj<<<dim3(8, 64), 256, 0, stream>>>(xv, wtv, bv, vt, 1, 1.0f);

    k_attn<<<512, 512, 0, stream>>>(qh, kh, vt, mb, attno);

    k_oproj<<<64, 256, 0, stream>>>(attno, wot, bo, out);
}